// Round 1
// baseline (645.317 us; speedup 1.0000x reference)
//
#include <hip/hip_runtime.h>
#include <hip/hip_bf16.h>

// ---------------------------------------------------------------------------
// LorentzMLR: logits = -arccosh(clip(x0*c0 - xf @ cs^T, 1+eps))
//   x:  (4096, 256) fp32       xf rows, x0[m] = sqrt(1+|xf_m|^2)
//   lt: (32000, 257) fp32      cs = lt[:,1:], c0[n] = sqrt(1+|cs_n|^2)
//   out:(4096, 32000) fp32
// Strategy: bf16 MFMA GEMM (K=256) + fused epilogue; norms in fp32.
// R1: m97-structure staging — global_load_lds width=16 into LINEAR LDS
//     (no pad; required by wave-uniform dest), nt stores for the 512 MB out.
// ---------------------------------------------------------------------------

#define M_ROWS   4096
#define N_COLS   32000
#define K_DIM    256
#define LT_LD    257
#define BK       32

typedef __bf16 v8bf __attribute__((ext_vector_type(8)));
typedef float  v4f  __attribute__((ext_vector_type(4)));

// ws layout (bytes)
#define XB_OFF   0u
#define CB_OFF   2097152u            // 4096*256*2
#define X0_OFF   18481152u           // CB_OFF + 32000*256*2
#define C0_OFF   18497536u           // X0_OFF + 4096*4
#define WS_NEED  18625536u           // C0_OFF + 32000*4

// --------------------------- prep: bf16 convert + norms ---------------------
__global__ __launch_bounds__(256) void prep_kernel(
    const float* __restrict__ x, const float* __restrict__ lt,
    __hip_bfloat16* __restrict__ xb, __hip_bfloat16* __restrict__ cb,
    float* __restrict__ x0, float* __restrict__ c0) {
  int row  = blockIdx.x * 4 + (threadIdx.x >> 6);   // one wave per row
  int lane = threadIdx.x & 63;
  if (row >= M_ROWS + N_COLS) return;

  float v[4];
  float ss = 0.0f;
  if (row < M_ROWS) {
    const float* src = x + (size_t)row * K_DIM;
#pragma unroll
    for (int k = 0; k < 4; ++k) { v[k] = src[k * 64 + lane]; ss += v[k] * v[k]; }
  } else {
    int c = row - M_ROWS;
    const float* src = lt + (size_t)c * LT_LD + 1;
#pragma unroll
    for (int k = 0; k < 4; ++k) { v[k] = src[k * 64 + lane]; ss += v[k] * v[k]; }
  }
  // wave-64 reduction
#pragma unroll
  for (int off = 32; off > 0; off >>= 1) ss += __shfl_down(ss, off, 64);

  __hip_bfloat16* dst = (row < M_ROWS) ? (xb + (size_t)row * K_DIM)
                                       : (cb + (size_t)(row - M_ROWS) * K_DIM);
#pragma unroll
  for (int k = 0; k < 4; ++k) dst[k * 64 + lane] = __float2bfloat16(v[k]);

  if (lane == 0) {
    float n = sqrtf(1.0f + ss);
    if (row < M_ROWS) x0[row] = n; else c0[row - M_ROWS] = n;
  }
}

// --------------------------- MFMA GEMM + epilogue ---------------------------
// Block tile 128(M) x 128(N), 256 threads = 4 waves in 2x2, wave tile 64x64.
// K loop: 8 iters of BK=32. Staging: global_load_lds dwordx4 (async DMA,
// no VGPR round-trip). LDS layout LINEAR [128][32] — global_load_lds writes
// wave-uniform base + lane*16, so no padding allowed (m104). The resulting
// ds_read conflicts are hidden behind the 2-barrier stage path (m230 regime).
__device__ __forceinline__ void gload_lds16(const unsigned short* g,
                                            unsigned short* l) {
  __builtin_amdgcn_global_load_lds(
      (const __attribute__((address_space(1))) void*)g,
      (__attribute__((address_space(3))) void*)l,
      16 /*bytes, literal*/, 0, 0);
}

__global__ __launch_bounds__(256) void gemm_kernel(
    const unsigned short* __restrict__ xb, const unsigned short* __restrict__ cb,
    const float* __restrict__ x0, const float* __restrict__ c0,
    float* __restrict__ out) {
  __shared__ __attribute__((aligned(16))) unsigned short Al[128 * BK]; // 8 KB
  __shared__ __attribute__((aligned(16))) unsigned short Bl[128 * BK]; // 8 KB

  const int tid  = threadIdx.x;
  const int w    = tid >> 6;
  const int lane = tid & 63;
  const int wm   = (w >> 1) * 64;       // wave M offset in tile
  const int wn   = (w & 1) * 64;        // wave N offset in tile
  const int lrow = lane & 15;
  const int lk   = (lane >> 4) * 8;

  const int mbase = blockIdx.y * 128;
  const int nbase = blockIdx.x * 128;

  // staging: thread tid covers LDS bytes [16*tid, 16*tid+16) of each half-tile
  // = row tid>>2 (+64 for round 1), k-chunk (tid&3)*8. Global src is per-lane.
  const unsigned short* gA = xb + (size_t)(mbase + (tid >> 2)) * K_DIM + (tid & 3) * 8;
  const unsigned short* gB = cb + (size_t)(nbase + (tid >> 2)) * K_DIM + (tid & 3) * 8;
  unsigned short* lA = &Al[tid * 8];     // byte offset 16*tid (uniform+lane*16)
  unsigned short* lB = &Bl[tid * 8];
  const size_t rstep = (size_t)64 * K_DIM;

  v4f acc[4][4];
#pragma unroll
  for (int i = 0; i < 4; ++i)
#pragma unroll
    for (int j = 0; j < 4; ++j) acc[i][j] = (v4f){0.f, 0.f, 0.f, 0.f};

#pragma unroll 1
  for (int ki = 0; ki < 8; ++ki) {
    if (ki) __syncthreads();            // previous iter's LDS reads done
    const int ko = ki * BK;
    gload_lds16(gA + ko,         lA);
    gload_lds16(gA + rstep + ko, lA + 64 * BK);
    gload_lds16(gB + ko,         lB);
    gload_lds16(gB + rstep + ko, lB + 64 * BK);
    __syncthreads();                    // vmcnt(0) drain -> LDS tile ready

    v8bf af[4], bf[4];
#pragma unroll
    for (int i = 0; i < 4; ++i)
      af[i] = *(const v8bf*)(&Al[(wm + i * 16 + lrow) * BK + lk]);
#pragma unroll
    for (int j = 0; j < 4; ++j)
      bf[j] = *(const v8bf*)(&Bl[(wn + j * 16 + lrow) * BK + lk]);
#pragma unroll
    for (int i = 0; i < 4; ++i)
#pragma unroll
      for (int j = 0; j < 4; ++j)
        acc[i][j] = __builtin_amdgcn_mfma_f32_16x16x32_bf16(af[i], bf[j], acc[i][j], 0, 0, 0);
  }

  // epilogue: C/D layout col=lane&15, row=(lane>>4)*4+reg  [verified m89]
  const int mloc = mbase + wm + (lane >> 4) * 4;
  const int nloc = nbase + wn + lrow;
  float cv[4];
#pragma unroll
  for (int j = 0; j < 4; ++j) cv[j] = c0[nloc + j * 16];

#pragma unroll
  for (int i = 0; i < 4; ++i) {
#pragma unroll
    for (int r = 0; r < 4; ++r) {
      const int m = mloc + i * 16 + r;
      const float xn = x0[m];
#pragma unroll
      for (int j = 0; j < 4; ++j) {
        float inner = xn * cv[j] - acc[i][j][r];
        float vv = fmaxf(inner, 1.000001f);
        float u  = vv + sqrtf(vv * vv - 1.0f);
        // streaming 512 MB: non-temporal keeps L2 for the B panel
        __builtin_nontemporal_store(-__logf(u),
                                    &out[(size_t)m * N_COLS + nloc + j * 16]);
      }
    }
  }
}

// --------------------------- fallback (ws too small) ------------------------
__global__ __launch_bounds__(256) void naive_kernel(
    const float* __restrict__ x, const float* __restrict__ lt,
    float* __restrict__ out) {
  int n = blockIdx.x * 256 + threadIdx.x;
  int m = blockIdx.y;
  if (n >= N_COLS) return;
  const float* xr = x + (size_t)m * K_DIM;
  const float* cr = lt + (size_t)n * LT_LD + 1;
  float ssx = 0.f, ssc = 0.f, dot = 0.f;
  for (int k = 0; k < K_DIM; ++k) {
    float xv = xr[k], cv = cr[k];
    ssx += xv * xv; ssc += cv * cv; dot += xv * cv;
  }
  float inner = sqrtf(1.f + ssx) * sqrtf(1.f + ssc) - dot;
  float vv = fmaxf(inner, 1.000001f);
  out[(size_t)m * N_COLS + n] = -logf(vv + sqrtf(vv * vv - 1.f));
}

// ---------------------------------------------------------------------------
extern "C" void kernel_launch(void* const* d_in, const int* in_sizes, int n_in,
                              void* d_out, int out_size, void* d_ws, size_t ws_size,
                              hipStream_t stream) {
  const float* x  = (const float*)d_in[0];
  const float* lt = (const float*)d_in[1];
  float* out = (float*)d_out;

  if (ws_size >= (size_t)WS_NEED) {
    char* ws = (char*)d_ws;
    __hip_bfloat16* xb = (__hip_bfloat16*)(ws + XB_OFF);
    __hip_bfloat16* cb = (__hip_bfloat16*)(ws + CB_OFF);
    float* x0 = (float*)(ws + X0_OFF);
    float* c0 = (float*)(ws + C0_OFF);

    prep_kernel<<<(M_ROWS + N_COLS) / 4, 256, 0, stream>>>(x, lt, xb, cb, x0, c0);
    gemm_kernel<<<dim3(N_COLS / 128, M_ROWS / 128), 256, 0, stream>>>(
        (const unsigned short*)xb, (const unsigned short*)cb, x0, c0, out);
  } else {
    naive_kernel<<<dim3((N_COLS + 255) / 256, M_ROWS), 256, 0, stream>>>(x, lt, out);
  }
}

// Round 2
// 606.410 us; speedup vs baseline: 1.0642x; 1.0642x over previous
//
#include <hip/hip_runtime.h>
#include <hip/hip_bf16.h>

// ---------------------------------------------------------------------------
// LorentzMLR: logits = -arccosh(clip(x0*c0 - xf @ cs^T, 1+eps))
//   x:  (4096, 256) fp32; lt: (32000, 257) fp32; out: (4096, 32000) fp32
// R2: theory = gemm is L3-fetch-bound (1.02 GB B-panel refetch, B >> 4MB L2).
//   (1) XCD strip schedule: pad to 256 N-tiles, xcd=b&7 owns every-8th
//       N-tile, M fastest -> B-tile L2-resident for 32 blocks, A panel L2-hit.
//   (2) double-buffered LDS, stage(ki+1) before compute(ki), 1 barrier/iter.
//   (3) conflict-free ds_read via pre-swizzled GLOBAL source + swizzled read
//       offsets (linear gload_lds dest, rule #21):
//       phys chunk p = (4r + ((c^r)&3)) ^ (r&4)   [16B chunks, row-major 32K]
// ---------------------------------------------------------------------------

#define M_ROWS   4096
#define N_COLS   32000
#define K_DIM    256
#define LT_LD    257
#define BK       32
#define NT_REAL  250
#define NT_PAD   256

typedef __bf16 v8bf __attribute__((ext_vector_type(8)));
typedef float  v4f  __attribute__((ext_vector_type(4)));

// ws layout (bytes)
#define XB_OFF   0u
#define CB_OFF   2097152u            // 4096*256*2
#define X0_OFF   18481152u           // CB_OFF + 32000*256*2
#define C0_OFF   18497536u           // X0_OFF + 4096*4
#define WS_NEED  18625536u           // C0_OFF + 32000*4

// --------------------------- prep: bf16 convert + norms ---------------------
__global__ __launch_bounds__(256) void prep_kernel(
    const float* __restrict__ x, const float* __restrict__ lt,
    __hip_bfloat16* __restrict__ xb, __hip_bfloat16* __restrict__ cb,
    float* __restrict__ x0, float* __restrict__ c0) {
  int row  = blockIdx.x * 4 + (threadIdx.x >> 6);   // one wave per row
  int lane = threadIdx.x & 63;
  if (row >= M_ROWS + N_COLS) return;

  float v[4];
  float ss = 0.0f;
  if (row < M_ROWS) {
    const float* src = x + (size_t)row * K_DIM;
#pragma unroll
    for (int k = 0; k < 4; ++k) { v[k] = src[k * 64 + lane]; ss += v[k] * v[k]; }
  } else {
    int c = row - M_ROWS;
    const float* src = lt + (size_t)c * LT_LD + 1;
#pragma unroll
    for (int k = 0; k < 4; ++k) { v[k] = src[k * 64 + lane]; ss += v[k] * v[k]; }
  }
#pragma unroll
  for (int off = 32; off > 0; off >>= 1) ss += __shfl_down(ss, off, 64);

  __hip_bfloat16* dst = (row < M_ROWS) ? (xb + (size_t)row * K_DIM)
                                       : (cb + (size_t)(row - M_ROWS) * K_DIM);
#pragma unroll
  for (int k = 0; k < 4; ++k) dst[k * 64 + lane] = __float2bfloat16(v[k]);

  if (lane == 0) {
    float n = sqrtf(1.0f + ss);
    if (row < M_ROWS) x0[row] = n; else c0[row - M_ROWS] = n;
  }
}

// --------------------------- MFMA GEMM + epilogue ---------------------------
__device__ __forceinline__ void gload_lds16(const unsigned short* g,
                                            unsigned short* l) {
  __builtin_amdgcn_global_load_lds(
      (const __attribute__((address_space(1))) void*)g,
      (__attribute__((address_space(3))) void*)l,
      16 /*bytes, literal*/, 0, 0);
}

// logical (row, c16chunk) -> physical 16B-chunk index. Rows 0..7 at fixed c
// land in 8 distinct bank-quads (2 lanes each = free).
__device__ __forceinline__ int swz_chunk(int row, int c) {
  return (row * 4 + ((c ^ row) & 3)) ^ (row & 4);
}

__global__ __launch_bounds__(256) void gemm_kernel(
    const unsigned short* __restrict__ xb, const unsigned short* __restrict__ cb,
    const float* __restrict__ x0, const float* __restrict__ c0,
    float* __restrict__ out) {
  __shared__ __attribute__((aligned(16))) unsigned short Al[2][128 * BK]; // 16KB
  __shared__ __attribute__((aligned(16))) unsigned short Bl[2][128 * BK]; // 16KB

  const int tid  = threadIdx.x;
  const int w    = tid >> 6;
  const int lane = tid & 63;
  const int wm   = (w >> 1) * 64;
  const int wn   = (w & 1) * 64;
  const int lrow = lane & 15;
  const int c16  = lane >> 4;

  // XCD strip schedule: xcd = b&7 (dispatch round-robin, m157), each XCD
  // sweeps M (32 blocks) per owned N-tile -> B-tile + A-panel L2-resident.
  const int b   = blockIdx.x;
  const int xcd = b & 7;
  const int i5  = b >> 3;
  const int nt  = (i5 >> 5) * 8 + xcd;
  const int mt  = i5 & 31;
  if (nt >= NT_REAL) return;             // padding tile (balance across XCDs)
  const int mbase = mt * 128;
  const int nbase = nt * 128;

  // staging: thread owns phys chunks p0=tid (rows 0..63) and p1=tid+256.
  // inverse swizzle p -> logical (rl, cl): rl = (p>>3)<<1 | ((p>>2 ^ p>>4)&1)
  const int p0  = tid, p1 = tid + 256;
  const int rl0 = ((p0 >> 3) << 1) | (((p0 >> 2) ^ (p0 >> 4)) & 1);
  const int cl0 = (p0 ^ rl0) & 3;
  const int rl1 = ((p1 >> 3) << 1) | (((p1 >> 2) ^ (p1 >> 4)) & 1);
  const int cl1 = (p1 ^ rl1) & 3;
  const unsigned short* gA0 = xb + (size_t)(mbase + rl0) * K_DIM + cl0 * 8;
  const unsigned short* gA1 = xb + (size_t)(mbase + rl1) * K_DIM + cl1 * 8;
  const unsigned short* gB0 = cb + (size_t)(nbase + rl0) * K_DIM + cl0 * 8;
  const unsigned short* gB1 = cb + (size_t)(nbase + rl1) * K_DIM + cl1 * 8;

  // read offsets (ushort index), ki-invariant
  int swA[4], swB[4];
#pragma unroll
  for (int i = 0; i < 4; ++i) swA[i] = swz_chunk(wm + i * 16 + lrow, c16) * 8;
#pragma unroll
  for (int j = 0; j < 4; ++j) swB[j] = swz_chunk(wn + j * 16 + lrow, c16) * 8;

  v4f acc[4][4];
#pragma unroll
  for (int i = 0; i < 4; ++i)
#pragma unroll
    for (int j = 0; j < 4; ++j) acc[i][j] = (v4f){0.f, 0.f, 0.f, 0.f};

  // prologue: stage ki=0 into buf 0
  gload_lds16(gA0, &Al[0][tid * 8]);
  gload_lds16(gA1, &Al[0][(tid + 256) * 8]);
  gload_lds16(gB0, &Bl[0][tid * 8]);
  gload_lds16(gB1, &Bl[0][(tid + 256) * 8]);
  __syncthreads();

#pragma unroll
  for (int ki = 0; ki < 8; ++ki) {
    const int cur = ki & 1;
    if (ki < 7) {                         // issue next tile BEFORE compute
      const int ko = (ki + 1) * BK;
      const int nb = cur ^ 1;
      gload_lds16(gA0 + ko, &Al[nb][tid * 8]);
      gload_lds16(gA1 + ko, &Al[nb][(tid + 256) * 8]);
      gload_lds16(gB0 + ko, &Bl[nb][tid * 8]);
      gload_lds16(gB1 + ko, &Bl[nb][(tid + 256) * 8]);
    }
    v8bf af[4], bf[4];
#pragma unroll
    for (int i = 0; i < 4; ++i) af[i] = *(const v8bf*)(&Al[cur][swA[i]]);
#pragma unroll
    for (int j = 0; j < 4; ++j) bf[j] = *(const v8bf*)(&Bl[cur][swB[j]]);
#pragma unroll
    for (int i = 0; i < 4; ++i)
#pragma unroll
      for (int j = 0; j < 4; ++j)
        acc[i][j] = __builtin_amdgcn_mfma_f32_16x16x32_bf16(af[i], bf[j], acc[i][j], 0, 0, 0);
    if (ki < 7) __syncthreads();          // drains vmcnt (stage) + lgkm (reads)
  }

  // epilogue: C/D layout col=lane&15, row=(lane>>4)*4+reg  [verified m89]
  const int mloc = mbase + wm + (lane >> 4) * 4;
  const int nloc = nbase + wn + lrow;
  float cv[4];
#pragma unroll
  for (int j = 0; j < 4; ++j) cv[j] = c0[nloc + j * 16];

#pragma unroll
  for (int i = 0; i < 4; ++i) {
#pragma unroll
    for (int r = 0; r < 4; ++r) {
      const int m = mloc + i * 16 + r;
      const float xn = x0[m];
#pragma unroll
      for (int j = 0; j < 4; ++j) {
        float inner = xn * cv[j] - acc[i][j][r];
        float vv = fmaxf(inner, 1.000001f);
        float u  = vv + sqrtf(vv * vv - 1.0f);
        // nt store: keep 512 MB stream out of L2 (B/A panels live there)
        __builtin_nontemporal_store(-__logf(u),
                                    &out[(size_t)m * N_COLS + nloc + j * 16]);
      }
    }
  }
}

// --------------------------- fallback (ws too small) ------------------------
__global__ __launch_bounds__(256) void naive_kernel(
    const float* __restrict__ x, const float* __restrict__ lt,
    float* __restrict__ out) {
  int n = blockIdx.x * 256 + threadIdx.x;
  int m = blockIdx.y;
  if (n >= N_COLS) return;
  const float* xr = x + (size_t)m * K_DIM;
  const float* cr = lt + (size_t)n * LT_LD + 1;
  float ssx = 0.f, ssc = 0.f, dot = 0.f;
  for (int k = 0; k < K_DIM; ++k) {
    float xv = xr[k], cv = cr[k];
    ssx += xv * xv; ssc += cv * cv; dot += xv * cv;
  }
  float inner = sqrtf(1.f + ssx) * sqrtf(1.f + ssc) - dot;
  float vv = fmaxf(inner, 1.000001f);
  out[(size_t)m * N_COLS + n] = -logf(vv + sqrtf(vv * vv - 1.f));
}

// ---------------------------------------------------------------------------
extern "C" void kernel_launch(void* const* d_in, const int* in_sizes, int n_in,
                              void* d_out, int out_size, void* d_ws, size_t ws_size,
                              hipStream_t stream) {
  const float* x  = (const float*)d_in[0];
  const float* lt = (const float*)d_in[1];
  float* out = (float*)d_out;

  if (ws_size >= (size_t)WS_NEED) {
    char* ws = (char*)d_ws;
    __hip_bfloat16* xb = (__hip_bfloat16*)(ws + XB_OFF);
    __hip_bfloat16* cb = (__hip_bfloat16*)(ws + CB_OFF);
    float* x0 = (float*)(ws + X0_OFF);
    float* c0 = (float*)(ws + C0_OFF);

    prep_kernel<<<(M_ROWS + N_COLS) / 4, 256, 0, stream>>>(x, lt, xb, cb, x0, c0);
    gemm_kernel<<<NT_PAD * 32, 256, 0, stream>>>(
        (const unsigned short*)xb, (const unsigned short*)cb, x0, c0, out);
  } else {
    naive_kernel<<<dim3((N_COLS + 255) / 256, M_ROWS), 256, 0, stream>>>(x, lt, out);
  }
}